// Round 4
// baseline (421.009 us; speedup 1.0000x reference)
//
#include <hip/hip_runtime.h>
#include <cstdint>
#include <cstddef>

typedef float f4 __attribute__((ext_vector_type(4)));

#define KCORES 12
#define DCAT   8192
#define RR     256     // R*R floats per matrix

// workspace layout (bytes)
#define WS_LOGZ  0
#define WS_NORM  256
#define WS_TABLE 16384
#define TABLE_BYTES ((size_t)KCORES * DCAT * RR * 4ull)
#define NEED_SP (WS_TABLE + TABLE_BYTES)

__device__ __forceinline__ float softplus_f(float x) {
    // matches jax.nn.softplus = max(x,0) + log1p(exp(-|x|))
    return fmaxf(x, 0.0f) + log1pf(expf(-fabsf(x)));
}

__device__ __forceinline__ void softplus4(f4& v) {
    v[0] = softplus_f(v[0]); v[1] = softplus_f(v[1]);
    v[2] = softplus_f(v[2]); v[3] = softplus_f(v[3]);
}

// ---------------------------------------------------------------------------
// Fused: softplus table build (optional) + per-core norm matrix reduction.
// grid = KCORES*16 blocks, 256 threads. Each block: 512 d-values of one core.
// ---------------------------------------------------------------------------
template<bool WRITE_TABLE>
__global__ __launch_bounds__(256)
void sp_norm_kernel(const float* __restrict__ lc, float* __restrict__ table,
                    float* __restrict__ norm) {
    int blk = blockIdx.x;
    int k = blk >> 4;            // core id
    int p = blk & 15;            // partition within core
    int t = threadIdx.x;
    size_t base = ((size_t)k * DCAT + (size_t)p * 512) * RR;   // float offset
    const f4* in4 = (const f4*)(lc + base);
    f4* out4 = WRITE_TABLE ? (f4*)(table + base) : nullptr;
    f4 acc = {0.f, 0.f, 0.f, 0.f};
    #pragma unroll 4
    for (int it = 0; it < 128; ++it) {       // 128 iters * 1024 elems = 512 d
        f4 v = in4[it * 256 + t];
        softplus4(v);
        if (WRITE_TABLE) out4[it * 256 + t] = v;
        acc += v;
    }
    // thread t always touches rc = 4t mod 256 .. +3 (independent of it)
    int rc0 = (t * 4) & 255;
    float* nk = norm + k * RR + rc0;
    atomicAdd(nk + 0, acc[0]);
    atomicAdd(nk + 1, acc[1]);
    atomicAdd(nk + 2, acc[2]);
    atomicAdd(nk + 3, acc[3]);
}

// ---------------------------------------------------------------------------
// Scale-tracked chain of the 12 norm matrices -> finite logZ in f32.
// (Raw f32 chain overflows ~8th factor; f64 np reference does not. We divide
//  out the running max each step and accumulate its log.)
// ---------------------------------------------------------------------------
__global__ __launch_bounds__(256)
void chain_kernel(const float* __restrict__ norm, float* __restrict__ logZ) {
    __shared__ float A[16][17];
    __shared__ float Bm[16][17];
    __shared__ float red[256];
    int t = threadIdx.x;
    int i = t >> 4, j = t & 15;
    float logscale = 0.f;        // tracked on thread 0 only (same code path)
    A[i][j] = norm[i * 16 + j];
    __syncthreads();
    for (int k = 1; k < KCORES; ++k) {
        Bm[i][j] = norm[k * RR + i * 16 + j];
        __syncthreads();
        float s = 0.f;
        #pragma unroll
        for (int r = 0; r < 16; ++r) s += A[i][r] * Bm[r][j];
        red[t] = s;
        __syncthreads();
        #pragma unroll
        for (int off = 128; off >= 1; off >>= 1) {
            if (t < off) red[t] = fmaxf(red[t], red[t + off]);
            __syncthreads();
        }
        float mx = red[0];
        A[i][j] = s / mx;        // safe: all A-reads for s finished pre-reduce
        if (t == 0) logscale += logf(mx);
        __syncthreads();
    }
    if (t == 0) {
        float tr = 0.f;
        #pragma unroll
        for (int r = 0; r < 16; ++r) tr += A[r][r];
        *logZ = logf(tr) + logscale;
    }
}

// ---------------------------------------------------------------------------
// Main kernel: one sample per wave; lane (i=l>>2, j4=l&3) owns prob[i][4j4..+3].
// Per-sample chain stays finite in f32 (worst-case entries ~2e19 << 3.4e38).
// ---------------------------------------------------------------------------
template<int Q>
__device__ __forceinline__ f4 quad_bcast(f4 v) {
    // broadcast lane (l & ~3) | Q within each quad: quad_perm ctrl = Q*0x55
    f4 r;
    #pragma unroll
    for (int c = 0; c < 4; ++c) {
        int x = __builtin_bit_cast(int, v[c]);
        x = __builtin_amdgcn_mov_dpp(x, Q * 0x55, 0xF, 0xF, false);
        r[c] = __builtin_bit_cast(float, x);
    }
    return r;
}

#define QSTEP(Q) { f4 crow = quad_bcast<Q>(cur);            \
    acc += crow[0] * mb[(4*(Q)+0)*4 + j4];                  \
    acc += crow[1] * mb[(4*(Q)+1)*4 + j4];                  \
    acc += crow[2] * mb[(4*(Q)+2)*4 + j4];                  \
    acc += crow[3] * mb[(4*(Q)+3)*4 + j4]; }

template<bool SP>
__global__ __launch_bounds__(256)
void trip_kernel(const int* __restrict__ index, const float* __restrict__ table,
                 const float* __restrict__ logZ, float* __restrict__ out, int B) {
    __shared__ f4 mbuf[2][4][64];    // double-buffered, one 16x16 matrix per wave
    int w = threadIdx.x >> 6;
    int lane = threadIdx.x & 63;
    int b = blockIdx.x * 4 + w;
    bool live = (b < B);
    int j4 = lane & 3;

    int myidx = 0;
    if (live && lane < KCORES) myidx = index[b * KCORES + lane];

    const f4* t4 = (const f4*)table;

    int d0 = __builtin_amdgcn_readlane(myidx, 0);
    f4 cur = t4[(size_t)d0 * 64 + lane];
    if (!SP) softplus4(cur);

    int d1 = __builtin_amdgcn_readlane(myidx, 1);
    f4 nxt = t4[((size_t)DCAT + d1) * 64 + lane];
    if (!SP) softplus4(nxt);

    #pragma unroll
    for (int k = 1; k < KCORES; ++k) {
        int p = (k - 1) & 1;
        mbuf[p][w][lane] = nxt;
        if (k + 1 < KCORES) {
            int dn = __builtin_amdgcn_readlane(myidx, k + 1);
            nxt = t4[((size_t)(k + 1) * DCAT + dn) * 64 + lane];
            if (!SP) softplus4(nxt);
        }
        __syncthreads();
        const f4* mb = &mbuf[p][w][0];
        f4 acc = {0.f, 0.f, 0.f, 0.f};
        QSTEP(0) QSTEP(1) QSTEP(2) QSTEP(3)
        cur = acc;
    }

    // trace: diagonal element r lives in lane (r<<2)|(r>>2), component r&3
    int i = lane >> 2;
    float contrib = 0.f;
    if ((i >> 2) == j4) contrib = cur[i & 3];
    #pragma unroll
    for (int off = 32; off >= 1; off >>= 1) contrib += __shfl_xor(contrib, off);
    if (live && lane == 0) out[b] = logf(contrib) - *logZ;
}

// ---------------------------------------------------------------------------
extern "C" void kernel_launch(void* const* d_in, const int* in_sizes, int n_in,
                              void* d_out, int out_size, void* d_ws, size_t ws_size,
                              hipStream_t stream) {
    const int*   index = (const int*)d_in[0];
    const float* lc    = (const float*)d_in[1];
    float* out = (float*)d_out;
    char*  ws  = (char*)d_ws;
    float* logZ  = (float*)(ws + WS_LOGZ);
    float* norm  = (float*)(ws + WS_NORM);
    float* table = (float*)(ws + WS_TABLE);

    int B = in_sizes[0] / KCORES;
    int nblk = (B + 3) / 4;

    hipMemsetAsync(norm, 0, KCORES * RR * sizeof(float), stream);

    bool sp = (ws_size >= NEED_SP);
    if (sp) {
        sp_norm_kernel<true><<<KCORES * 16, 256, 0, stream>>>(lc, table, norm);
        chain_kernel<<<1, 256, 0, stream>>>(norm, logZ);
        trip_kernel<true><<<nblk, 256, 0, stream>>>(index, table, logZ, out, B);
    } else {
        sp_norm_kernel<false><<<KCORES * 16, 256, 0, stream>>>(lc, nullptr, norm);
        chain_kernel<<<1, 256, 0, stream>>>(norm, logZ);
        trip_kernel<false><<<nblk, 256, 0, stream>>>(index, lc, logZ, out, B);
    }
}

// Round 5
// 328.211 us; speedup vs baseline: 1.2827x; 1.2827x over previous
//
#include <hip/hip_runtime.h>
#include <cstdint>
#include <cstddef>

typedef float f4 __attribute__((ext_vector_type(4)));

#define KCORES 12
#define DCAT   8192
#define RR     256     // R*R floats per matrix

// workspace layout (bytes)
#define WS_LOGZ  0
#define WS_NORM  256
#define WS_TABLE 16384
#define TABLE_BYTES ((size_t)KCORES * DCAT * RR * 4ull)
#define NEED_SP (WS_TABLE + TABLE_BYTES)

__device__ __forceinline__ float softplus_f(float x) {
    // matches jax.nn.softplus = max(x,0) + log1p(exp(-|x|))
    return fmaxf(x, 0.0f) + log1pf(expf(-fabsf(x)));
}

__device__ __forceinline__ void softplus4(f4& v) {
    v[0] = softplus_f(v[0]); v[1] = softplus_f(v[1]);
    v[2] = softplus_f(v[2]); v[3] = softplus_f(v[3]);
}

// ---------------------------------------------------------------------------
// Fused: softplus table build (optional) + per-core norm matrix reduction.
// grid = KCORES*128 = 1536 blocks (6/CU, ~75% occupancy), 256 threads.
// Each block: 64 d-matrices of one core. Round-4 profile showed the old
// 192-block grid at 8.4% occupancy / 786 GB/s — latency-bound, not BW-bound.
// ---------------------------------------------------------------------------
template<bool WRITE_TABLE>
__global__ __launch_bounds__(256)
void sp_norm_kernel(const float* __restrict__ lc, float* __restrict__ table,
                    float* __restrict__ norm) {
    int blk = blockIdx.x;
    int k = blk >> 7;            // core id = blk / 128
    int p = blk & 127;           // partition within core
    int t = threadIdx.x;
    int w = t >> 6, lane = t & 63;
    size_t base = ((size_t)k * DCAT + (size_t)p * 64) * RR;   // float offset
    const f4* in4 = (const f4*)(lc + base);
    f4* out4 = WRITE_TABLE ? (f4*)(table + base) : nullptr;
    f4 acc = {0.f, 0.f, 0.f, 0.f};
    #pragma unroll
    for (int it = 0; it < 16; ++it) {        // 16 iters * 1024 floats = 64 d
        f4 v = in4[it * 256 + t];
        softplus4(v);
        if (WRITE_TABLE) out4[it * 256 + t] = v;
        acc += v;
    }
    // thread t always touches rc = 4*lane .. +3 (same for every wave)
    __shared__ f4 red[4][64];
    red[w][lane] = acc;
    __syncthreads();
    if (w == 0) {
        f4 s = red[0][lane] + red[1][lane] + red[2][lane] + red[3][lane];
        float* nk = norm + k * RR + lane * 4;
        atomicAdd(nk + 0, s[0]);
        atomicAdd(nk + 1, s[1]);
        atomicAdd(nk + 2, s[2]);
        atomicAdd(nk + 3, s[3]);
    }
}

// ---------------------------------------------------------------------------
// Scale-tracked chain of the 12 norm matrices -> finite logZ in f32.
// (Raw f32 chain overflows ~8th factor; f64 np reference does not. We divide
//  out the running max each step and accumulate its log.)
// ---------------------------------------------------------------------------
__global__ __launch_bounds__(256)
void chain_kernel(const float* __restrict__ norm, float* __restrict__ logZ) {
    __shared__ float A[16][17];
    __shared__ float Bm[16][17];
    __shared__ float red[256];
    int t = threadIdx.x;
    int i = t >> 4, j = t & 15;
    float logscale = 0.f;        // tracked on thread 0 only (same code path)
    A[i][j] = norm[i * 16 + j];
    __syncthreads();
    for (int k = 1; k < KCORES; ++k) {
        Bm[i][j] = norm[k * RR + i * 16 + j];
        __syncthreads();
        float s = 0.f;
        #pragma unroll
        for (int r = 0; r < 16; ++r) s += A[i][r] * Bm[r][j];
        red[t] = s;
        __syncthreads();
        #pragma unroll
        for (int off = 128; off >= 1; off >>= 1) {
            if (t < off) red[t] = fmaxf(red[t], red[t + off]);
            __syncthreads();
        }
        float mx = red[0];
        A[i][j] = s / mx;        // safe: all A-reads for s finished pre-reduce
        if (t == 0) logscale += logf(mx);
        __syncthreads();
    }
    if (t == 0) {
        float tr = 0.f;
        #pragma unroll
        for (int r = 0; r < 16; ++r) tr += A[r][r];
        *logZ = logf(tr) + logscale;
    }
}

// ---------------------------------------------------------------------------
// Main kernel: one sample per wave; lane (i=l>>2, j4=l&3) owns prob[i][4j4..+3].
// Per-sample chain stays finite in f32 (worst-case entries ~2e19 << 3.4e38).
// No __syncthreads: each wave touches only mbuf[*][w]; per-wave ds_write ->
// ds_read ordering via s_waitcnt lgkmcnt(0) (+"memory" clobber; consumers are
// ds_read memory ops so the clobber orders them — rule-18 hazard not in play).
// ---------------------------------------------------------------------------
template<int Q>
__device__ __forceinline__ f4 quad_bcast(f4 v) {
    // broadcast lane (l & ~3) | Q within each quad: quad_perm ctrl = Q*0x55
    f4 r;
    #pragma unroll
    for (int c = 0; c < 4; ++c) {
        int x = __builtin_bit_cast(int, v[c]);
        x = __builtin_amdgcn_mov_dpp(x, Q * 0x55, 0xF, 0xF, false);
        r[c] = __builtin_bit_cast(float, x);
    }
    return r;
}

#define QSTEP(Q) { f4 crow = quad_bcast<Q>(cur);            \
    acc += crow[0] * mb[(4*(Q)+0)*4 + j4];                  \
    acc += crow[1] * mb[(4*(Q)+1)*4 + j4];                  \
    acc += crow[2] * mb[(4*(Q)+2)*4 + j4];                  \
    acc += crow[3] * mb[(4*(Q)+3)*4 + j4]; }

template<bool SP>
__global__ __launch_bounds__(256)
void trip_kernel(const int* __restrict__ index, const float* __restrict__ table,
                 const float* __restrict__ logZ, float* __restrict__ out, int B) {
    __shared__ f4 mbuf[2][4][64];    // double-buffered, one 16x16 matrix per wave
    int w = threadIdx.x >> 6;
    int lane = threadIdx.x & 63;
    int b = blockIdx.x * 4 + w;
    bool live = (b < B);
    int j4 = lane & 3;

    int myidx = 0;
    if (live && lane < KCORES) myidx = index[b * KCORES + lane];

    const f4* t4 = (const f4*)table;

    int d0 = __builtin_amdgcn_readlane(myidx, 0);
    f4 cur = t4[(size_t)d0 * 64 + lane];
    if (!SP) softplus4(cur);

    int d1 = __builtin_amdgcn_readlane(myidx, 1);
    f4 nxt = t4[((size_t)DCAT + d1) * 64 + lane];
    if (!SP) softplus4(nxt);

    #pragma unroll
    for (int k = 1; k < KCORES; ++k) {
        int p = (k - 1) & 1;
        mbuf[p][w][lane] = nxt;
        if (k + 1 < KCORES) {
            int dn = __builtin_amdgcn_readlane(myidx, k + 1);
            nxt = t4[((size_t)(k + 1) * DCAT + dn) * 64 + lane];
            if (!SP) softplus4(nxt);
        }
        // per-wave LDS RAW fence (no cross-wave sharing -> no block barrier)
        asm volatile("s_waitcnt lgkmcnt(0)" ::: "memory");
        const f4* mb = &mbuf[p][w][0];
        f4 acc = {0.f, 0.f, 0.f, 0.f};
        QSTEP(0) QSTEP(1) QSTEP(2) QSTEP(3)
        cur = acc;
    }

    // trace: diagonal element r lives in lane (r<<2)|(r>>2), component r&3
    int i = lane >> 2;
    float contrib = 0.f;
    if ((i >> 2) == j4) contrib = cur[i & 3];
    #pragma unroll
    for (int off = 32; off >= 1; off >>= 1) contrib += __shfl_xor(contrib, off);
    if (live && lane == 0) out[b] = logf(contrib) - *logZ;
}

// ---------------------------------------------------------------------------
extern "C" void kernel_launch(void* const* d_in, const int* in_sizes, int n_in,
                              void* d_out, int out_size, void* d_ws, size_t ws_size,
                              hipStream_t stream) {
    const int*   index = (const int*)d_in[0];
    const float* lc    = (const float*)d_in[1];
    float* out = (float*)d_out;
    char*  ws  = (char*)d_ws;
    float* logZ  = (float*)(ws + WS_LOGZ);
    float* norm  = (float*)(ws + WS_NORM);
    float* table = (float*)(ws + WS_TABLE);

    int B = in_sizes[0] / KCORES;
    int nblk = (B + 3) / 4;

    hipMemsetAsync(norm, 0, KCORES * RR * sizeof(float), stream);

    bool sp = (ws_size >= NEED_SP);
    if (sp) {
        sp_norm_kernel<true><<<KCORES * 128, 256, 0, stream>>>(lc, table, norm);
        chain_kernel<<<1, 256, 0, stream>>>(norm, logZ);
        trip_kernel<true><<<nblk, 256, 0, stream>>>(index, table, logZ, out, B);
    } else {
        sp_norm_kernel<false><<<KCORES * 128, 256, 0, stream>>>(lc, nullptr, norm);
        chain_kernel<<<1, 256, 0, stream>>>(norm, logZ);
        trip_kernel<false><<<nblk, 256, 0, stream>>>(index, lc, logZ, out, B);
    }
}